// Round 11
// baseline (1397.977 us; speedup 1.0000x reference)
//
#include <hip/hip_runtime.h>
#include <hip/hip_bf16.h>

// EarthAttention2D on MI355X (gfx950).
// B_WIN=2048, N=128, DIM=512, HEADS=16, hd=32, M = 2048*128 = 262144.
// Pipeline: cvt_x (x->bf16) + prep (weights->bf16, epb gather)
//        -> QKV GEMM (BK=32, single 16KiB buffer -> 7 blocks/CU,
//           swapped-operand MFMA -> direct packed stores, head-major
//           Q/K/V[b,h,n,d])
//        -> fused window attention (r9-proven)
//        -> proj GEMM (same loop, float4 stores, f32 out).
//
// LESSONS ENCODED:
//  - r6: never pin __launch_bounds__ min-waves above the acc working set.
//  - r8: epilogue must not branch acc usage across barriers.
//  - r9: blocks/CU is THE lever in this short-K regime; LDS was the binder
//        (VGPR 72 allows 7 waves/SIMD, 32KiB LDS capped at 5 blocks/CU).
//  - r11: 16KiB LDS (BK=32) + swapped-operand epilogue (lane owns 4
//        consecutive cols -> uint2/float4 direct stores, no LDS restage).
//
// BK=32 LDS swizzle (r5-verified): LDS row r chunk s holds global chunk
// s ^ ((r>>1)&3); GLDS dest linear, SOURCE carries inverse swizzle (m173).
// ds_read col chunk = g ^ ((lo>>1)&3) -> quarter-wave spreads over all 8
// 128B bank-groups (2 lanes each = free, m136).
//
// Swapped MFMA: acc[i][j] = mfma16(bq[j], af[i], acc) gives lane
// C[m = wm*64+i*16+lo][n = wn*64+j*16+g*4+ii] -> 4 consecutive n per reg.

typedef short short8 __attribute__((ext_vector_type(8)));
typedef float f32x4 __attribute__((ext_vector_type(4)));
typedef unsigned short u16;
typedef unsigned int u32;

__device__ __forceinline__ u16 f2bf(float f) {
    __bf16 h = (__bf16)f;                    // RNE fptrunc -> v_cvt on gfx950
    union { __bf16 b; u16 u; } v; v.b = h;
    return v.u;
}

__device__ __forceinline__ f32x4 mfma16(short8 a, short8 b, f32x4 c) {
    return __builtin_amdgcn_mfma_f32_16x16x32_bf16(a, b, c, 0, 0, 0);
}

// async global->LDS, 16B per lane, dest = wave-uniform base + lane*16
#define GLDS16(gsrc, ldst)                                                  \
    __builtin_amdgcn_global_load_lds(                                       \
        (const __attribute__((address_space(1))) void*)(gsrc),              \
        (__attribute__((address_space(3))) void*)(ldst), 16, 0, 0)

// ---------------------------------------------------------------- cvt_x ----
__global__ __launch_bounds__(256) void cvt_x_kernel(
    const float4* __restrict__ xin, int4* __restrict__ xbf)
{
    int idx = blockIdx.x * 256 + threadIdx.x;           // unit = 8 floats
    for (; idx < 16777216; idx += 8192 * 256) {
        const float4 a = xin[idx * 2], b = xin[idx * 2 + 1];
        int4 o;
        o.x = (u32)f2bf(a.x) | ((u32)f2bf(a.y) << 16);
        o.y = (u32)f2bf(a.z) | ((u32)f2bf(a.w) << 16);
        o.z = (u32)f2bf(b.x) | ((u32)f2bf(b.y) << 16);
        o.w = (u32)f2bf(b.z) | ((u32)f2bf(b.w) << 16);
        xbf[idx] = o;
    }
}

// ---------------------------------------------------------------- prep ----
__global__ __launch_bounds__(256) void prep_kernel(
    const float* __restrict__ qkv_w, const float* __restrict__ proj_w,
    const float* __restrict__ btab, const int* __restrict__ pidx,
    u16* __restrict__ qkvw_bf, u16* __restrict__ projw_bf,
    float* __restrict__ epb)
{
    const int i = blockIdx.x * 256 + threadIdx.x;    // grid = 3072*256 = 786432
    qkvw_bf[i] = f2bf(qkv_w[i]);
    if (i < 512 * 512) projw_bf[i] = f2bf(proj_w[i]);
    if (i < 16 * 128 * 128) {
        const int rc = i & 16383, h = i >> 14;
        epb[i] = btab[pidx[rc] * 128 + 64 + h];      // bias_table[idx][TOW/2=4][h]
    }
}

// ---------------------------------------------------------------- GEMM ----
// C[M,Nn] = A[M,K] @ Bt[Nn,K]^T (+bias).  128x128 tile, BK=32, 4 waves.
// LDS: single buffer A[128][32] + B[128][32] = 16 KiB -> 7 blocks/CU
// (VGPR-capped at 512/VGPR waves/SIMD).  2 barriers/tile (r2-proven loop).
//
// EPI_QKV: tsel = bn>>2 (0=Q,1=K,2=V), 4 heads per tile; direct uint2
// stores (4 bf16/lane, consecutive d) to out[((b*16+h)*128+n)*32+d],
// scale=qscale iff tsel==0.
// else: direct float4 stores (+bias) to Cv (perfectly coalesced: 4 lanes
// per row cover 64B).

template<bool EPI_QKV>
__global__ __launch_bounds__(256) void gemm_bt(
    const u16* __restrict__ A, const u16* __restrict__ Bt,
    const float* __restrict__ bias, void* __restrict__ Cv,
    u16* __restrict__ kb, u16* __restrict__ vb,
    const int Nn, const int K, const float qscale)
{
    __shared__ __attribute__((aligned(16))) char sm[16384];

    const int tid = threadIdx.x;
    const int lane = tid & 63;
    const int w = tid >> 6;
    const int lo = lane & 15, g = lane >> 4;
    const int wm = w >> 1, wn = w & 1;
    const int wofs = __builtin_amdgcn_readfirstlane(w) * 1024;
    const int ntile = Nn >> 7;

    int wg = blockIdx.x;
    {   // bijective XCD swizzle (gridDim % 8 == 0 for all launches)
        const int cpx = gridDim.x >> 3;
        wg = (wg & 7) * cpx + (wg >> 3);
    }
    const int bm = wg / ntile, bn = wg % ntile;
    const size_t m0 = (size_t)bm << 7;
    const int n0 = bn << 7;
    const int nk = K >> 5;                               // 16

    // staging (r5-verified): row rs = w*16 + (lane>>2), LDS chunk = lane&3,
    // source chunk = (lane&3) ^ ((lane>>3)&3)  (inverse swizzle)
    const int rs = w * 16 + (lane >> 2);
    const int c8 = ((lane & 3) ^ ((lane >> 3) & 3)) * 8;
    const u16* pa0 = A + (m0 + rs) * (size_t)K + c8;
    const u16* pa1 = pa0 + (size_t)64 * K;
    const u16* pb0 = Bt + (size_t)(n0 + rs) * K + c8;
    const u16* pb1 = pb0 + (size_t)64 * K;

#define STAGE(kt)                                                          \
    do {                                                                   \
        const int ko = (kt) << 5;                                          \
        char* d = sm + wofs;                                               \
        GLDS16(pa0 + ko, d);                                               \
        GLDS16(pa1 + ko, d + 4096);                                        \
        GLDS16(pb0 + ko, d + 8192);                                        \
        GLDS16(pb1 + ko, d + 12288);                                       \
    } while (0)

    f32x4 acc[4][4] = {};   // acc[i][j]: C[m=i-frag+lo][n=j-frag+g*4+ii]

    // ds_read col swizzle: chunk = g ^ ((lo>>1)&3)  (constant per lane)
    const int csw16 = (g ^ ((lo >> 1) & 3)) << 4;

    STAGE(0);
    for (int kt = 0;;) {
        __syncthreads();            // drains vmcnt -> tile kt resident
        short8 af[4], bq[4];
#pragma unroll
        for (int i = 0; i < 4; ++i) {
            af[i] = *(const short8*)(sm + (wm * 64 + i * 16 + lo) * 64 + csw16);
            bq[i] = *(const short8*)(sm + 8192
                                     + (wn * 64 + i * 16 + lo) * 64 + csw16);
        }
#pragma unroll
        for (int i = 0; i < 4; ++i)
#pragma unroll
            for (int j = 0; j < 4; ++j)
                acc[i][j] = mfma16(bq[j], af[i], acc[i][j]);  // swapped: C^T frag
        if (++kt == nk) break;
        __syncthreads();            // all reads done; LDS free for next tile
        STAGE(kt);
    }
#undef STAGE

    if constexpr (EPI_QKV) {
        const int b16 = ((int)(m0 >> 7)) * 16;
        const int tsel = bn >> 2;                        // 0=q,1=k,2=v (uniform)
        const int h0 = (bn & 3) << 2;
        u16* outb = (tsel == 0) ? (u16*)Cv : (tsel == 1) ? kb : vb;
        const float sc = (tsel == 0) ? qscale : 1.0f;
#pragma unroll
        for (int j = 0; j < 4; ++j) {
            const int nn = wn * 64 + j * 16 + g * 4;     // col base (mult of 4)
            const float4 bv = *(const float4*)(bias + n0 + nn);
            const int hl = nn >> 5, d0 = nn & 31;
#pragma unroll
            for (int i = 0; i < 4; ++i) {
                const size_t m = wm * 64 + i * 16 + lo;
                uint2 pk;
                pk.x = (u32)f2bf((acc[i][j][0] + bv.x) * sc)
                     | ((u32)f2bf((acc[i][j][1] + bv.y) * sc) << 16);
                pk.y = (u32)f2bf((acc[i][j][2] + bv.z) * sc)
                     | ((u32)f2bf((acc[i][j][3] + bv.w) * sc) << 16);
                *(uint2*)(outb + ((size_t)(b16 + h0 + hl) * 128 + m) * 32 + d0)
                    = pk;
            }
        }
    } else {
        float* Cg = (float*)Cv;
#pragma unroll
        for (int j = 0; j < 4; ++j) {
            const int nn = wn * 64 + j * 16 + g * 4;
            const float4 bv = *(const float4*)(bias + n0 + nn);
#pragma unroll
            for (int i = 0; i < 4; ++i) {
                const size_t m = m0 + wm * 64 + i * 16 + lo;
                float4 v;
                v.x = acc[i][j][0] + bv.x;
                v.y = acc[i][j][1] + bv.y;
                v.z = acc[i][j][2] + bv.z;
                v.w = acc[i][j][3] + bv.w;
                *(float4*)(Cg + m * (size_t)Nn + n0 + nn) = v;
            }
        }
    }
}

// ----------------------------------------------------------- attention ----
// r9-proven version.  One block (4 waves) per (b, h).  Inputs head-major:
// Q/K/V[b,h,n,d].  Q/K staged via global_load_lds with quarter-wave swizzle
// (64B rows); V loaded int4-coalesced and transposed into padded [32][136].
// Union LDS 43520 B -> 3 blocks/CU.
__global__ __launch_bounds__(256) void attn_kernel(
    const u16* __restrict__ qbuf, const u16* __restrict__ kbuf,
    const u16* __restrict__ vbuf, const float* __restrict__ epb,
    u16* __restrict__ aout)
{
    __shared__ __attribute__((aligned(16))) char smem[43520];
    u16 (*Vt)[136]      = (u16(*)[136])smem;                 // [32][136]
    char* Qs            = smem + 8704;                       // [128][32] swz
    char* Ks            = smem + 16896;                      // [128][32] swz
    u16 (*Ps)[32][136]  = (u16(*)[32][136])(smem + 8704);    // [4][32][136]
    u16 (*Os)[32]       = (u16(*)[32])smem;                  // [128][32]

    const int h = blockIdx.x >> 11;
    const int b = blockIdx.x & 2047;
    const int tid = threadIdx.x;
    const int lane = tid & 63, w = tid >> 6;
    const int lo = lane & 15, g = lane >> 4;
    const int wu = __builtin_amdgcn_readfirstlane(w);

    const size_t hb = (size_t)(b * 16 + h) * 4096;
    const u16* qp = qbuf + hb;
    const u16* kp = kbuf + hb;
    const u16* vp = vbuf + hb;

    // Q/K via global_load_lds with inverse-swizzled source
    const int c8 = ((lane & 3) ^ ((lane >> 3) & 3)) * 8;
    const int rofs = (lane >> 2) * 32;
#pragma unroll
    for (int cc = 0; cc < 2; ++cc) {
        const int ch = wu * 2 + cc;
        GLDS16(qp + ch * 512 + rofs + c8, Qs + ch * 1024);
        GLDS16(kp + ch * 512 + rofs + c8, Ks + ch * 1024);
    }
    // V: coalesced int4 loads, transpose via scalar LDS writes
#pragma unroll
    for (int it = 0; it < 2; ++it) {
        const int idx = tid + it * 256;          // 0..511
        const int n = idx >> 2, d8 = (idx & 3) * 8;
        union { int4 q; u16 u[8]; } vu;
        vu.q = *(const int4*)(vp + n * 32 + d8);
#pragma unroll
        for (int j = 0; j < 8; ++j) Vt[d8 + j][n] = vu.u[j];
    }
    __syncthreads();

    const int r0 = w * 32;
    const int csw16 = (g ^ ((lo >> 1) & 3)) << 4;   // ds_read col swizzle

    // ---- S = Q @ K^T ----
    short8 aq[2], bk[8];
    aq[0] = *(const short8*)(Qs + (r0 + lo) * 64 + csw16);
    aq[1] = *(const short8*)(Qs + (r0 + 16 + lo) * 64 + csw16);
#pragma unroll
    for (int j = 0; j < 8; ++j)
        bk[j] = *(const short8*)(Ks + (j * 16 + lo) * 64 + csw16);

    f32x4 acc[2][8];
#pragma unroll
    for (int j = 0; j < 8; ++j) {
        f32x4 z = {0.f, 0.f, 0.f, 0.f};
        acc[0][j] = mfma16(aq[0], bk[j], z);
        acc[1][j] = mfma16(aq[1], bk[j], z);
    }

    // ---- bias + row max ----
    const float* eb = epb + (h << 14);
    float mrow[2][4], rsum[2][4];
#pragma unroll
    for (int mt = 0; mt < 2; ++mt)
#pragma unroll
        for (int ii = 0; ii < 4; ++ii) { mrow[mt][ii] = -1e30f; rsum[mt][ii] = 0.f; }

#pragma unroll
    for (int mt = 0; mt < 2; ++mt)
#pragma unroll
        for (int j = 0; j < 8; ++j)
#pragma unroll
            for (int ii = 0; ii < 4; ++ii) {
                const int r = r0 + mt * 16 + g * 4 + ii;
                const int c = j * 16 + lo;
                const float sv = acc[mt][j][ii] + eb[(r << 7) + c];
                acc[mt][j][ii] = sv;
                mrow[mt][ii] = fmaxf(mrow[mt][ii], sv);
            }
#pragma unroll
    for (int d = 1; d < 16; d <<= 1)
#pragma unroll
        for (int mt = 0; mt < 2; ++mt)
#pragma unroll
            for (int ii = 0; ii < 4; ++ii)
                mrow[mt][ii] = fmaxf(mrow[mt][ii], __shfl_xor(mrow[mt][ii], d, 64));

    __syncthreads();   // all waves done reading Qs/Ks -> Ps may overwrite

    // ---- exp -> Ps (per-wave private region), row sums ----
#pragma unroll
    for (int mt = 0; mt < 2; ++mt)
#pragma unroll
        for (int j = 0; j < 8; ++j)
#pragma unroll
            for (int ii = 0; ii < 4; ++ii) {
                const float p = __expf(acc[mt][j][ii] - mrow[mt][ii]);
                rsum[mt][ii] += p;
                Ps[w][mt * 16 + g * 4 + ii][j * 16 + lo] = f2bf(p);
            }
#pragma unroll
    for (int d = 1; d < 16; d <<= 1)
#pragma unroll
        for (int mt = 0; mt < 2; ++mt)
#pragma unroll
            for (int ii = 0; ii < 4; ++ii)
                rsum[mt][ii] += __shfl_xor(rsum[mt][ii], d, 64);

    // ---- O = P @ V ----
    f32x4 o[2][2] = {};
#pragma unroll
    for (int kk = 0; kk < 4; ++kk) {
        short8 av[2];
        av[0] = *(const short8*)(&Ps[w][lo][kk * 32 + g * 8]);
        av[1] = *(const short8*)(&Ps[w][16 + lo][kk * 32 + g * 8]);
#pragma unroll
        for (int dt = 0; dt < 2; ++dt) {
            const short8 bv = *(const short8*)(&Vt[dt * 16 + lo][kk * 32 + g * 8]);
            o[0][dt] = mfma16(av[0], bv, o[0][dt]);
            o[1][dt] = mfma16(av[1], bv, o[1][dt]);
        }
    }

    __syncthreads();   // all waves done reading Vt -> Os may overwrite

    // ---- normalize -> Os, coalesced int4 stores ----
#pragma unroll
    for (int mt = 0; mt < 2; ++mt)
#pragma unroll
        for (int dt = 0; dt < 2; ++dt)
#pragma unroll
            for (int ii = 0; ii < 4; ++ii)
                Os[r0 + mt * 16 + g * 4 + ii][dt * 16 + lo] =
                    f2bf(o[mt][dt][ii] / rsum[mt][ii]);
    __syncthreads();

    u16* op = aout + (size_t)b * 128 * 512 + h * 32;
#pragma unroll
    for (int it = 0; it < 2; ++it) {
        const int idx = tid + it * 256;          // 0..511
        const int r = idx >> 2, c = (idx & 3) * 8;
        *(int4*)(op + (size_t)r * 512 + c) = *(const int4*)(&Os[r][c]);
    }
}

// -------------------------------------------------------------- launch ----
extern "C" void kernel_launch(void* const* d_in, const int* in_sizes, int n_in,
                              void* d_out, int out_size, void* d_ws, size_t ws_size,
                              hipStream_t stream)
{
    const float* x      = (const float*)d_in[0];
    const float* qkv_w  = (const float*)d_in[1];
    const float* qkv_b  = (const float*)d_in[2];
    const float* proj_w = (const float*)d_in[3];
    const float* proj_b = (const float*)d_in[4];
    const float* btab   = (const float*)d_in[5];
    const int*   pidx   = (const int*)d_in[6];

    // workspace layout (bytes), total 1,076,887,552
    // xbf aliases attnbuf: x_bf16 is dead before attn writes its output.
    char* ws = (char*)d_ws;
    u16*   xbf      = (u16*)(ws);                        // 268,435,456
    u16*   attnbuf  = (u16*)(ws);                        // (alias)
    u16*   qkvw_bf  = (u16*)(ws + 268435456);            //   1,572,864
    u16*   projw_bf = (u16*)(ws + 270008320);            //     524,288
    float* epb      = (float*)(ws + 270532608);          //   1,048,576
    u16*   qbuf     = (u16*)(ws + 271581184);            // 268,435,456
    u16*   kbuf     = (u16*)(ws + 540016640);            // 268,435,456
    u16*   vbuf     = (u16*)(ws + 808452096);            // 268,435,456

    const float qscale = 0.17677669529663687f;           // 32^-0.5

    cvt_x_kernel<<<dim3(8192), dim3(256), 0, stream>>>(
        (const float4*)x, (int4*)xbf);

    prep_kernel<<<dim3(3072), dim3(256), 0, stream>>>(
        qkv_w, proj_w, btab, pidx, qkvw_bf, projw_bf, epb);

    // QKV: [262144,512]bf16 @ [1536,512]bf16^T -> Q/K/V head-major buffers
    gemm_bt<true><<<dim3(2048 * 12), dim3(256), 0, stream>>>(
        xbf, qkvw_bf, qkv_b, qbuf, kbuf, vbuf, 1536, 512, qscale);

    // fused window attention: 2048 windows x 16 heads
    attn_kernel<<<dim3(32768), dim3(256), 0, stream>>>(
        qbuf, kbuf, vbuf, epb, attnbuf);

    // proj: [262144,512]bf16 @ [512,512]bf16^T -> f32 (+bias)
    gemm_bt<false><<<dim3(2048 * 4), dim3(256), 0, stream>>>(
        attnbuf, projw_bf, proj_b, d_out, nullptr, nullptr, 512, 512, 1.0f);
}

// Round 12
// 1393.599 us; speedup vs baseline: 1.0031x; 1.0031x over previous
//
#include <hip/hip_runtime.h>
#include <hip/hip_bf16.h>

// EarthAttention2D on MI355X (gfx950).
// B_WIN=2048, N=128, DIM=512, HEADS=16, hd=32, M = 2048*128 = 262144.
// Pipeline: cvt_x (x->bf16) + prep (weights->bf16, epb gather)
//        -> QKV GEMM (BK=32, single 16KiB buffer -> 7 blocks/CU,
//           swapped-operand MFMA -> direct packed stores, head-major
//           Q/K/V[b,h,n,d])
//        -> fused window attention (r9-proven)
//        -> proj GEMM (same loop, float4 stores, f32 out).
//
// LESSONS ENCODED:
//  - r6: never pin __launch_bounds__ min-waves above the acc working set.
//  - r8: epilogue must not branch acc usage across barriers.
//  - r9: blocks/CU is THE lever in this short-K regime; LDS was the binder
//        (VGPR 72 allows 7 waves/SIMD, 32KiB LDS capped at 5 blocks/CU).
//  - r11: 16KiB LDS (BK=32) + swapped-operand epilogue (lane owns 4
//        consecutive cols -> uint2/float4 direct stores, no LDS restage).
//
// BK=32 LDS swizzle (r5-verified): LDS row r chunk s holds global chunk
// s ^ ((r>>1)&3); GLDS dest linear, SOURCE carries inverse swizzle (m173).
// ds_read col chunk = g ^ ((lo>>1)&3) -> quarter-wave spreads over all 8
// 128B bank-groups (2 lanes each = free, m136).
//
// Swapped MFMA: acc[i][j] = mfma16(bq[j], af[i], acc) gives lane
// C[m = wm*64+i*16+lo][n = wn*64+j*16+g*4+ii] -> 4 consecutive n per reg.

typedef short short8 __attribute__((ext_vector_type(8)));
typedef float f32x4 __attribute__((ext_vector_type(4)));
typedef unsigned short u16;
typedef unsigned int u32;

__device__ __forceinline__ u16 f2bf(float f) {
    __bf16 h = (__bf16)f;                    // RNE fptrunc -> v_cvt on gfx950
    union { __bf16 b; u16 u; } v; v.b = h;
    return v.u;
}

__device__ __forceinline__ f32x4 mfma16(short8 a, short8 b, f32x4 c) {
    return __builtin_amdgcn_mfma_f32_16x16x32_bf16(a, b, c, 0, 0, 0);
}

// async global->LDS, 16B per lane, dest = wave-uniform base + lane*16
#define GLDS16(gsrc, ldst)                                                  \
    __builtin_amdgcn_global_load_lds(                                       \
        (const __attribute__((address_space(1))) void*)(gsrc),              \
        (__attribute__((address_space(3))) void*)(ldst), 16, 0, 0)

// ---------------------------------------------------------------- cvt_x ----
__global__ __launch_bounds__(256) void cvt_x_kernel(
    const float4* __restrict__ xin, int4* __restrict__ xbf)
{
    int idx = blockIdx.x * 256 + threadIdx.x;           // unit = 8 floats
    for (; idx < 16777216; idx += 8192 * 256) {
        const float4 a = xin[idx * 2], b = xin[idx * 2 + 1];
        int4 o;
        o.x = (u32)f2bf(a.x) | ((u32)f2bf(a.y) << 16);
        o.y = (u32)f2bf(a.z) | ((u32)f2bf(a.w) << 16);
        o.z = (u32)f2bf(b.x) | ((u32)f2bf(b.y) << 16);
        o.w = (u32)f2bf(b.z) | ((u32)f2bf(b.w) << 16);
        xbf[idx] = o;
    }
}

// ---------------------------------------------------------------- prep ----
__global__ __launch_bounds__(256) void prep_kernel(
    const float* __restrict__ qkv_w, const float* __restrict__ proj_w,
    const float* __restrict__ btab, const int* __restrict__ pidx,
    u16* __restrict__ qkvw_bf, u16* __restrict__ projw_bf,
    float* __restrict__ epb)
{
    const int i = blockIdx.x * 256 + threadIdx.x;    // grid = 3072*256 = 786432
    qkvw_bf[i] = f2bf(qkv_w[i]);
    if (i < 512 * 512) projw_bf[i] = f2bf(proj_w[i]);
    if (i < 16 * 128 * 128) {
        const int rc = i & 16383, h = i >> 14;
        epb[i] = btab[pidx[rc] * 128 + 64 + h];      // bias_table[idx][TOW/2=4][h]
    }
}

// ---------------------------------------------------------------- GEMM ----
// C[M,Nn] = A[M,K] @ Bt[Nn,K]^T (+bias).  128x128 tile, BK=32, 4 waves.
// LDS: single buffer A[128][32] + B[128][32] = 16 KiB -> 7 blocks/CU
// (VGPR-capped at 512/VGPR waves/SIMD).  2 barriers/tile (r2-proven loop).
//
// EPI_QKV: tsel = bn>>2 (0=Q,1=K,2=V), 4 heads per tile; direct uint2
// stores (4 bf16/lane, consecutive d) to out[((b*16+h)*128+n)*32+d],
// scale=qscale iff tsel==0.
// else: direct float4 stores (+bias) to Cv (perfectly coalesced: 4 lanes
// per row cover 64B).

template<bool EPI_QKV>
__global__ __launch_bounds__(256) void gemm_bt(
    const u16* __restrict__ A, const u16* __restrict__ Bt,
    const float* __restrict__ bias, void* __restrict__ Cv,
    u16* __restrict__ kb, u16* __restrict__ vb,
    const int Nn, const int K, const float qscale)
{
    __shared__ __attribute__((aligned(16))) char sm[16384];

    const int tid = threadIdx.x;
    const int lane = tid & 63;
    const int w = tid >> 6;
    const int lo = lane & 15, g = lane >> 4;
    const int wm = w >> 1, wn = w & 1;
    const int wofs = __builtin_amdgcn_readfirstlane(w) * 1024;
    const int ntile = Nn >> 7;

    int wg = blockIdx.x;
    {   // bijective XCD swizzle (gridDim % 8 == 0 for all launches)
        const int cpx = gridDim.x >> 3;
        wg = (wg & 7) * cpx + (wg >> 3);
    }
    const int bm = wg / ntile, bn = wg % ntile;
    const size_t m0 = (size_t)bm << 7;
    const int n0 = bn << 7;
    const int nk = K >> 5;                               // 16

    // staging (r5-verified): row rs = w*16 + (lane>>2), LDS chunk = lane&3,
    // source chunk = (lane&3) ^ ((lane>>3)&3)  (inverse swizzle)
    const int rs = w * 16 + (lane >> 2);
    const int c8 = ((lane & 3) ^ ((lane >> 3) & 3)) * 8;
    const u16* pa0 = A + (m0 + rs) * (size_t)K + c8;
    const u16* pa1 = pa0 + (size_t)64 * K;
    const u16* pb0 = Bt + (size_t)(n0 + rs) * K + c8;
    const u16* pb1 = pb0 + (size_t)64 * K;

#define STAGE(kt)                                                          \
    do {                                                                   \
        const int ko = (kt) << 5;                                          \
        char* d = sm + wofs;                                               \
        GLDS16(pa0 + ko, d);                                               \
        GLDS16(pa1 + ko, d + 4096);                                        \
        GLDS16(pb0 + ko, d + 8192);                                        \
        GLDS16(pb1 + ko, d + 12288);                                       \
    } while (0)

    f32x4 acc[4][4] = {};   // acc[i][j]: C[m=i-frag+lo][n=j-frag+g*4+ii]

    // ds_read col swizzle: chunk = g ^ ((lo>>1)&3)  (constant per lane)
    const int csw16 = (g ^ ((lo >> 1) & 3)) << 4;

    STAGE(0);
    for (int kt = 0;;) {
        __syncthreads();            // drains vmcnt -> tile kt resident
        short8 af[4], bq[4];
#pragma unroll
        for (int i = 0; i < 4; ++i) {
            af[i] = *(const short8*)(sm + (wm * 64 + i * 16 + lo) * 64 + csw16);
            bq[i] = *(const short8*)(sm + 8192
                                     + (wn * 64 + i * 16 + lo) * 64 + csw16);
        }
#pragma unroll
        for (int i = 0; i < 4; ++i)
#pragma unroll
            for (int j = 0; j < 4; ++j)
                acc[i][j] = mfma16(bq[j], af[i], acc[i][j]);  // swapped: C^T frag
        if (++kt == nk) break;
        __syncthreads();            // all reads done; LDS free for next tile
        STAGE(kt);
    }
#undef STAGE

    if constexpr (EPI_QKV) {
        const int b16 = ((int)(m0 >> 7)) * 16;
        const int tsel = bn >> 2;                        // 0=q,1=k,2=v (uniform)
        const int h0 = (bn & 3) << 2;
        u16* outb = (tsel == 0) ? (u16*)Cv : (tsel == 1) ? kb : vb;
        const float sc = (tsel == 0) ? qscale : 1.0f;
#pragma unroll
        for (int j = 0; j < 4; ++j) {
            const int nn = wn * 64 + j * 16 + g * 4;     // col base (mult of 4)
            const float4 bv = *(const float4*)(bias + n0 + nn);
            const int hl = nn >> 5, d0 = nn & 31;
#pragma unroll
            for (int i = 0; i < 4; ++i) {
                const size_t m = wm * 64 + i * 16 + lo;
                uint2 pk;
                pk.x = (u32)f2bf((acc[i][j][0] + bv.x) * sc)
                     | ((u32)f2bf((acc[i][j][1] + bv.y) * sc) << 16);
                pk.y = (u32)f2bf((acc[i][j][2] + bv.z) * sc)
                     | ((u32)f2bf((acc[i][j][3] + bv.w) * sc) << 16);
                *(uint2*)(outb + ((size_t)(b16 + h0 + hl) * 128 + m) * 32 + d0)
                    = pk;
            }
        }
    } else {
        float* Cg = (float*)Cv;
#pragma unroll
        for (int j = 0; j < 4; ++j) {
            const int nn = wn * 64 + j * 16 + g * 4;
            const float4 bv = *(const float4*)(bias + n0 + nn);
#pragma unroll
            for (int i = 0; i < 4; ++i) {
                const size_t m = m0 + wm * 64 + i * 16 + lo;
                float4 v;
                v.x = acc[i][j][0] + bv.x;
                v.y = acc[i][j][1] + bv.y;
                v.z = acc[i][j][2] + bv.z;
                v.w = acc[i][j][3] + bv.w;
                *(float4*)(Cg + m * (size_t)Nn + n0 + nn) = v;
            }
        }
    }
}

// ----------------------------------------------------------- attention ----
// r9-proven version.  One block (4 waves) per (b, h).  Inputs head-major:
// Q/K/V[b,h,n,d].  Q/K staged via global_load_lds with quarter-wave swizzle
// (64B rows); V loaded int4-coalesced and transposed into padded [32][136].
// Union LDS 43520 B -> 3 blocks/CU.
__global__ __launch_bounds__(256) void attn_kernel(
    const u16* __restrict__ qbuf, const u16* __restrict__ kbuf,
    const u16* __restrict__ vbuf, const float* __restrict__ epb,
    u16* __restrict__ aout)
{
    __shared__ __attribute__((aligned(16))) char smem[43520];
    u16 (*Vt)[136]      = (u16(*)[136])smem;                 // [32][136]
    char* Qs            = smem + 8704;                       // [128][32] swz
    char* Ks            = smem + 16896;                      // [128][32] swz
    u16 (*Ps)[32][136]  = (u16(*)[32][136])(smem + 8704);    // [4][32][136]
    u16 (*Os)[32]       = (u16(*)[32])smem;                  // [128][32]

    const int h = blockIdx.x >> 11;
    const int b = blockIdx.x & 2047;
    const int tid = threadIdx.x;
    const int lane = tid & 63, w = tid >> 6;
    const int lo = lane & 15, g = lane >> 4;
    const int wu = __builtin_amdgcn_readfirstlane(w);

    const size_t hb = (size_t)(b * 16 + h) * 4096;
    const u16* qp = qbuf + hb;
    const u16* kp = kbuf + hb;
    const u16* vp = vbuf + hb;

    // Q/K via global_load_lds with inverse-swizzled source
    const int c8 = ((lane & 3) ^ ((lane >> 3) & 3)) * 8;
    const int rofs = (lane >> 2) * 32;
#pragma unroll
    for (int cc = 0; cc < 2; ++cc) {
        const int ch = wu * 2 + cc;
        GLDS16(qp + ch * 512 + rofs + c8, Qs + ch * 1024);
        GLDS16(kp + ch * 512 + rofs + c8, Ks + ch * 1024);
    }
    // V: coalesced int4 loads, transpose via scalar LDS writes
#pragma unroll
    for (int it = 0; it < 2; ++it) {
        const int idx = tid + it * 256;          // 0..511
        const int n = idx >> 2, d8 = (idx & 3) * 8;
        union { int4 q; u16 u[8]; } vu;
        vu.q = *(const int4*)(vp + n * 32 + d8);
#pragma unroll
        for (int j = 0; j < 8; ++j) Vt[d8 + j][n] = vu.u[j];
    }
    __syncthreads();

    const int r0 = w * 32;
    const int csw16 = (g ^ ((lo >> 1) & 3)) << 4;   // ds_read col swizzle

    // ---- S = Q @ K^T ----
    short8 aq[2], bk[8];
    aq[0] = *(const short8*)(Qs + (r0 + lo) * 64 + csw16);
    aq[1] = *(const short8*)(Qs + (r0 + 16 + lo) * 64 + csw16);
#pragma unroll
    for (int j = 0; j < 8; ++j)
        bk[j] = *(const short8*)(Ks + (j * 16 + lo) * 64 + csw16);

    f32x4 acc[2][8];
#pragma unroll
    for (int j = 0; j < 8; ++j) {
        f32x4 z = {0.f, 0.f, 0.f, 0.f};
        acc[0][j] = mfma16(aq[0], bk[j], z);
        acc[1][j] = mfma16(aq[1], bk[j], z);
    }

    // ---- bias + row max ----
    const float* eb = epb + (h << 14);
    float mrow[2][4], rsum[2][4];
#pragma unroll
    for (int mt = 0; mt < 2; ++mt)
#pragma unroll
        for (int ii = 0; ii < 4; ++ii) { mrow[mt][ii] = -1e30f; rsum[mt][ii] = 0.f; }

#pragma unroll
    for (int mt = 0; mt < 2; ++mt)
#pragma unroll
        for (int j = 0; j < 8; ++j)
#pragma unroll
            for (int ii = 0; ii < 4; ++ii) {
                const int r = r0 + mt * 16 + g * 4 + ii;
                const int c = j * 16 + lo;
                const float sv = acc[mt][j][ii] + eb[(r << 7) + c];
                acc[mt][j][ii] = sv;
                mrow[mt][ii] = fmaxf(mrow[mt][ii], sv);
            }
#pragma unroll
    for (int d = 1; d < 16; d <<= 1)
#pragma unroll
        for (int mt = 0; mt < 2; ++mt)
#pragma unroll
            for (int ii = 0; ii < 4; ++ii)
                mrow[mt][ii] = fmaxf(mrow[mt][ii], __shfl_xor(mrow[mt][ii], d, 64));

    __syncthreads();   // all waves done reading Qs/Ks -> Ps may overwrite

    // ---- exp -> Ps (per-wave private region), row sums ----
#pragma unroll
    for (int mt = 0; mt < 2; ++mt)
#pragma unroll
        for (int j = 0; j < 8; ++j)
#pragma unroll
            for (int ii = 0; ii < 4; ++ii) {
                const float p = __expf(acc[mt][j][ii] - mrow[mt][ii]);
                rsum[mt][ii] += p;
                Ps[w][mt * 16 + g * 4 + ii][j * 16 + lo] = f2bf(p);
            }
#pragma unroll
    for (int d = 1; d < 16; d <<= 1)
#pragma unroll
        for (int mt = 0; mt < 2; ++mt)
#pragma unroll
            for (int ii = 0; ii < 4; ++ii)
                rsum[mt][ii] += __shfl_xor(rsum[mt][ii], d, 64);

    // ---- O = P @ V ----
    f32x4 o[2][2] = {};
#pragma unroll
    for (int kk = 0; kk < 4; ++kk) {
        short8 av[2];
        av[0] = *(const short8*)(&Ps[w][lo][kk * 32 + g * 8]);
        av[1] = *(const short8*)(&Ps[w][16 + lo][kk * 32 + g * 8]);
#pragma unroll
        for (int dt = 0; dt < 2; ++dt) {
            const short8 bv = *(const short8*)(&Vt[dt * 16 + lo][kk * 32 + g * 8]);
            o[0][dt] = mfma16(av[0], bv, o[0][dt]);
            o[1][dt] = mfma16(av[1], bv, o[1][dt]);
        }
    }

    __syncthreads();   // all waves done reading Vt -> Os may overwrite

    // ---- normalize -> Os, coalesced int4 stores ----
#pragma unroll
    for (int mt = 0; mt < 2; ++mt)
#pragma unroll
        for (int dt = 0; dt < 2; ++dt)
#pragma unroll
            for (int ii = 0; ii < 4; ++ii)
                Os[r0 + mt * 16 + g * 4 + ii][dt * 16 + lo] =
                    f2bf(o[mt][dt][ii] / rsum[mt][ii]);
    __syncthreads();

    u16* op = aout + (size_t)b * 128 * 512 + h * 32;
#pragma unroll
    for (int it = 0; it < 2; ++it) {
        const int idx = tid + it * 256;          // 0..511
        const int r = idx >> 2, c = (idx & 3) * 8;
        *(int4*)(op + (size_t)r * 512 + c) = *(const int4*)(&Os[r][c]);
    }
}

// -------------------------------------------------------------- launch ----
extern "C" void kernel_launch(void* const* d_in, const int* in_sizes, int n_in,
                              void* d_out, int out_size, void* d_ws, size_t ws_size,
                              hipStream_t stream)
{
    const float* x      = (const float*)d_in[0];
    const float* qkv_w  = (const float*)d_in[1];
    const float* qkv_b  = (const float*)d_in[2];
    const float* proj_w = (const float*)d_in[3];
    const float* proj_b = (const float*)d_in[4];
    const float* btab   = (const float*)d_in[5];
    const int*   pidx   = (const int*)d_in[6];

    // workspace layout (bytes), total 1,076,887,552
    // xbf aliases attnbuf: x_bf16 is dead before attn writes its output.
    char* ws = (char*)d_ws;
    u16*   xbf      = (u16*)(ws);                        // 268,435,456
    u16*   attnbuf  = (u16*)(ws);                        // (alias)
    u16*   qkvw_bf  = (u16*)(ws + 268435456);            //   1,572,864
    u16*   projw_bf = (u16*)(ws + 270008320);            //     524,288
    float* epb      = (float*)(ws + 270532608);          //   1,048,576
    u16*   qbuf     = (u16*)(ws + 271581184);            // 268,435,456
    u16*   kbuf     = (u16*)(ws + 540016640);            // 268,435,456
    u16*   vbuf     = (u16*)(ws + 808452096);            // 268,435,456

    const float qscale = 0.17677669529663687f;           // 32^-0.5

    cvt_x_kernel<<<dim3(8192), dim3(256), 0, stream>>>(
        (const float4*)x, (int4*)xbf);

    prep_kernel<<<dim3(3072), dim3(256), 0, stream>>>(
        qkv_w, proj_w, btab, pidx, qkvw_bf, projw_bf, epb);

    // QKV: [262144,512]bf16 @ [1536,512]bf16^T -> Q/K/V head-major buffers
    gemm_bt<true><<<dim3(2048 * 12), dim3(256), 0, stream>>>(
        xbf, qkvw_bf, qkv_b, qbuf, kbuf, vbuf, 1536, 512, qscale);

    // fused window attention: 2048 windows x 16 heads
    attn_kernel<<<dim3(32768), dim3(256), 0, stream>>>(
        qbuf, kbuf, vbuf, epb, attnbuf);

    // proj: [262144,512]bf16 @ [512,512]bf16^T -> f32 (+bias)
    gemm_bt<false><<<dim3(2048 * 4), dim3(256), 0, stream>>>(
        attnbuf, projw_bf, proj_b, d_out, nullptr, nullptr, 512, 512, 1.0f);
}

// Round 13
// 1392.192 us; speedup vs baseline: 1.0042x; 1.0010x over previous
//
#include <hip/hip_runtime.h>
#include <hip/hip_bf16.h>

// EarthAttention2D on MI355X (gfx950).
// B_WIN=2048, N=128, DIM=512, HEADS=16, hd=32, M = 2048*128 = 262144.
// Pipeline: cvt_x (x->bf16) + prep (weights->bf16, epb gather)
//        -> QKV GEMM (BK=32, single 16KiB buffer -> 7 blocks/CU,
//           swapped-operand MFMA -> direct packed stores, head-major
//           Q/K/V[b,h,n,d])
//        -> fused window attention (r9-proven)
//        -> proj GEMM (same loop, float4 stores, f32 out).
//
// LESSONS ENCODED:
//  - r6: never pin __launch_bounds__ min-waves above the acc working set.
//  - r8: epilogue must not branch acc usage across barriers.
//  - r9: blocks/CU is THE lever in this short-K regime; LDS was the binder
//        (VGPR 72 allows 7 waves/SIMD, 32KiB LDS capped at 5 blocks/CU).
//  - r11: 16KiB LDS (BK=32) + swapped-operand epilogue (lane owns 4
//        consecutive cols -> uint2/float4 direct stores, no LDS restage).
//
// BK=32 LDS swizzle (r5-verified): LDS row r chunk s holds global chunk
// s ^ ((r>>1)&3); GLDS dest linear, SOURCE carries inverse swizzle (m173).
// ds_read col chunk = g ^ ((lo>>1)&3) -> quarter-wave spreads over all 8
// 128B bank-groups (2 lanes each = free, m136).
//
// Swapped MFMA: acc[i][j] = mfma16(bq[j], af[i], acc) gives lane
// C[m = wm*64+i*16+lo][n = wn*64+j*16+g*4+ii] -> 4 consecutive n per reg.

typedef short short8 __attribute__((ext_vector_type(8)));
typedef float f32x4 __attribute__((ext_vector_type(4)));
typedef unsigned short u16;
typedef unsigned int u32;

__device__ __forceinline__ u16 f2bf(float f) {
    __bf16 h = (__bf16)f;                    // RNE fptrunc -> v_cvt on gfx950
    union { __bf16 b; u16 u; } v; v.b = h;
    return v.u;
}

__device__ __forceinline__ f32x4 mfma16(short8 a, short8 b, f32x4 c) {
    return __builtin_amdgcn_mfma_f32_16x16x32_bf16(a, b, c, 0, 0, 0);
}

// async global->LDS, 16B per lane, dest = wave-uniform base + lane*16
#define GLDS16(gsrc, ldst)                                                  \
    __builtin_amdgcn_global_load_lds(                                       \
        (const __attribute__((address_space(1))) void*)(gsrc),              \
        (__attribute__((address_space(3))) void*)(ldst), 16, 0, 0)

// ---------------------------------------------------------------- cvt_x ----
__global__ __launch_bounds__(256) void cvt_x_kernel(
    const float4* __restrict__ xin, int4* __restrict__ xbf)
{
    int idx = blockIdx.x * 256 + threadIdx.x;           // unit = 8 floats
    for (; idx < 16777216; idx += 8192 * 256) {
        const float4 a = xin[idx * 2], b = xin[idx * 2 + 1];
        int4 o;
        o.x = (u32)f2bf(a.x) | ((u32)f2bf(a.y) << 16);
        o.y = (u32)f2bf(a.z) | ((u32)f2bf(a.w) << 16);
        o.z = (u32)f2bf(b.x) | ((u32)f2bf(b.y) << 16);
        o.w = (u32)f2bf(b.z) | ((u32)f2bf(b.w) << 16);
        xbf[idx] = o;
    }
}

// ---------------------------------------------------------------- prep ----
__global__ __launch_bounds__(256) void prep_kernel(
    const float* __restrict__ qkv_w, const float* __restrict__ proj_w,
    const float* __restrict__ btab, const int* __restrict__ pidx,
    u16* __restrict__ qkvw_bf, u16* __restrict__ projw_bf,
    float* __restrict__ epb)
{
    const int i = blockIdx.x * 256 + threadIdx.x;    // grid = 3072*256 = 786432
    qkvw_bf[i] = f2bf(qkv_w[i]);
    if (i < 512 * 512) projw_bf[i] = f2bf(proj_w[i]);
    if (i < 16 * 128 * 128) {
        const int rc = i & 16383, h = i >> 14;
        epb[i] = btab[pidx[rc] * 128 + 64 + h];      // bias_table[idx][TOW/2=4][h]
    }
}

// ---------------------------------------------------------------- GEMM ----
// C[M,Nn] = A[M,K] @ Bt[Nn,K]^T (+bias).  128x128 tile, BK=32, 4 waves.
// LDS: single buffer A[128][32] + B[128][32] = 16 KiB -> 7 blocks/CU
// (VGPR-capped at 512/VGPR waves/SIMD).  2 barriers/tile (r2-proven loop).
//
// EPI_QKV: tsel = bn>>2 (0=Q,1=K,2=V), 4 heads per tile; direct uint2
// stores (4 bf16/lane, consecutive d) to out[((b*16+h)*128+n)*32+d],
// scale=qscale iff tsel==0.
// else: direct float4 stores (+bias) to Cv (perfectly coalesced: 4 lanes
// per row cover 64B).

template<bool EPI_QKV>
__global__ __launch_bounds__(256) void gemm_bt(
    const u16* __restrict__ A, const u16* __restrict__ Bt,
    const float* __restrict__ bias, void* __restrict__ Cv,
    u16* __restrict__ kb, u16* __restrict__ vb,
    const int Nn, const int K, const float qscale)
{
    __shared__ __attribute__((aligned(16))) char sm[16384];

    const int tid = threadIdx.x;
    const int lane = tid & 63;
    const int w = tid >> 6;
    const int lo = lane & 15, g = lane >> 4;
    const int wm = w >> 1, wn = w & 1;
    const int wofs = __builtin_amdgcn_readfirstlane(w) * 1024;
    const int ntile = Nn >> 7;

    int wg = blockIdx.x;
    {   // bijective XCD swizzle (gridDim % 8 == 0 for all launches)
        const int cpx = gridDim.x >> 3;
        wg = (wg & 7) * cpx + (wg >> 3);
    }
    const int bm = wg / ntile, bn = wg % ntile;
    const size_t m0 = (size_t)bm << 7;
    const int n0 = bn << 7;
    const int nk = K >> 5;                               // 16

    // staging (r5-verified): row rs = w*16 + (lane>>2), LDS chunk = lane&3,
    // source chunk = (lane&3) ^ ((lane>>3)&3)  (inverse swizzle)
    const int rs = w * 16 + (lane >> 2);
    const int c8 = ((lane & 3) ^ ((lane >> 3) & 3)) * 8;
    const u16* pa0 = A + (m0 + rs) * (size_t)K + c8;
    const u16* pa1 = pa0 + (size_t)64 * K;
    const u16* pb0 = Bt + (size_t)(n0 + rs) * K + c8;
    const u16* pb1 = pb0 + (size_t)64 * K;

#define STAGE(kt)                                                          \
    do {                                                                   \
        const int ko = (kt) << 5;                                          \
        char* d = sm + wofs;                                               \
        GLDS16(pa0 + ko, d);                                               \
        GLDS16(pa1 + ko, d + 4096);                                        \
        GLDS16(pb0 + ko, d + 8192);                                        \
        GLDS16(pb1 + ko, d + 12288);                                       \
    } while (0)

    f32x4 acc[4][4] = {};   // acc[i][j]: C[m=i-frag+lo][n=j-frag+g*4+ii]

    // ds_read col swizzle: chunk = g ^ ((lo>>1)&3)  (constant per lane)
    const int csw16 = (g ^ ((lo >> 1) & 3)) << 4;

    STAGE(0);
    for (int kt = 0;;) {
        __syncthreads();            // drains vmcnt -> tile kt resident
        short8 af[4], bq[4];
#pragma unroll
        for (int i = 0; i < 4; ++i) {
            af[i] = *(const short8*)(sm + (wm * 64 + i * 16 + lo) * 64 + csw16);
            bq[i] = *(const short8*)(sm + 8192
                                     + (wn * 64 + i * 16 + lo) * 64 + csw16);
        }
#pragma unroll
        for (int i = 0; i < 4; ++i)
#pragma unroll
            for (int j = 0; j < 4; ++j)
                acc[i][j] = mfma16(bq[j], af[i], acc[i][j]);  // swapped: C^T frag
        if (++kt == nk) break;
        __syncthreads();            // all reads done; LDS free for next tile
        STAGE(kt);
    }
#undef STAGE

    if constexpr (EPI_QKV) {
        const int b16 = ((int)(m0 >> 7)) * 16;
        const int tsel = bn >> 2;                        // 0=q,1=k,2=v (uniform)
        const int h0 = (bn & 3) << 2;
        u16* outb = (tsel == 0) ? (u16*)Cv : (tsel == 1) ? kb : vb;
        const float sc = (tsel == 0) ? qscale : 1.0f;
#pragma unroll
        for (int j = 0; j < 4; ++j) {
            const int nn = wn * 64 + j * 16 + g * 4;     // col base (mult of 4)
            const float4 bv = *(const float4*)(bias + n0 + nn);
            const int hl = nn >> 5, d0 = nn & 31;
#pragma unroll
            for (int i = 0; i < 4; ++i) {
                const size_t m = wm * 64 + i * 16 + lo;
                uint2 pk;
                pk.x = (u32)f2bf((acc[i][j][0] + bv.x) * sc)
                     | ((u32)f2bf((acc[i][j][1] + bv.y) * sc) << 16);
                pk.y = (u32)f2bf((acc[i][j][2] + bv.z) * sc)
                     | ((u32)f2bf((acc[i][j][3] + bv.w) * sc) << 16);
                *(uint2*)(outb + ((size_t)(b16 + h0 + hl) * 128 + m) * 32 + d0)
                    = pk;
            }
        }
    } else {
        float* Cg = (float*)Cv;
#pragma unroll
        for (int j = 0; j < 4; ++j) {
            const int nn = wn * 64 + j * 16 + g * 4;
            const float4 bv = *(const float4*)(bias + n0 + nn);
#pragma unroll
            for (int i = 0; i < 4; ++i) {
                const size_t m = m0 + wm * 64 + i * 16 + lo;
                float4 v;
                v.x = acc[i][j][0] + bv.x;
                v.y = acc[i][j][1] + bv.y;
                v.z = acc[i][j][2] + bv.z;
                v.w = acc[i][j][3] + bv.w;
                *(float4*)(Cg + m * (size_t)Nn + n0 + nn) = v;
            }
        }
    }
}

// ----------------------------------------------------------- attention ----
// r9-proven version.  One block (4 waves) per (b, h).  Inputs head-major:
// Q/K/V[b,h,n,d].  Q/K staged via global_load_lds with quarter-wave swizzle
// (64B rows); V loaded int4-coalesced and transposed into padded [32][136].
// Union LDS 43520 B -> 3 blocks/CU.
__global__ __launch_bounds__(256) void attn_kernel(
    const u16* __restrict__ qbuf, const u16* __restrict__ kbuf,
    const u16* __restrict__ vbuf, const float* __restrict__ epb,
    u16* __restrict__ aout)
{
    __shared__ __attribute__((aligned(16))) char smem[43520];
    u16 (*Vt)[136]      = (u16(*)[136])smem;                 // [32][136]
    char* Qs            = smem + 8704;                       // [128][32] swz
    char* Ks            = smem + 16896;                      // [128][32] swz
    u16 (*Ps)[32][136]  = (u16(*)[32][136])(smem + 8704);    // [4][32][136]
    u16 (*Os)[32]       = (u16(*)[32])smem;                  // [128][32]

    const int h = blockIdx.x >> 11;
    const int b = blockIdx.x & 2047;
    const int tid = threadIdx.x;
    const int lane = tid & 63, w = tid >> 6;
    const int lo = lane & 15, g = lane >> 4;
    const int wu = __builtin_amdgcn_readfirstlane(w);

    const size_t hb = (size_t)(b * 16 + h) * 4096;
    const u16* qp = qbuf + hb;
    const u16* kp = kbuf + hb;
    const u16* vp = vbuf + hb;

    // Q/K via global_load_lds with inverse-swizzled source
    const int c8 = ((lane & 3) ^ ((lane >> 3) & 3)) * 8;
    const int rofs = (lane >> 2) * 32;
#pragma unroll
    for (int cc = 0; cc < 2; ++cc) {
        const int ch = wu * 2 + cc;
        GLDS16(qp + ch * 512 + rofs + c8, Qs + ch * 1024);
        GLDS16(kp + ch * 512 + rofs + c8, Ks + ch * 1024);
    }
    // V: coalesced int4 loads, transpose via scalar LDS writes
#pragma unroll
    for (int it = 0; it < 2; ++it) {
        const int idx = tid + it * 256;          // 0..511
        const int n = idx >> 2, d8 = (idx & 3) * 8;
        union { int4 q; u16 u[8]; } vu;
        vu.q = *(const int4*)(vp + n * 32 + d8);
#pragma unroll
        for (int j = 0; j < 8; ++j) Vt[d8 + j][n] = vu.u[j];
    }
    __syncthreads();

    const int r0 = w * 32;
    const int csw16 = (g ^ ((lo >> 1) & 3)) << 4;   // ds_read col swizzle

    // ---- S = Q @ K^T ----
    short8 aq[2], bk[8];
    aq[0] = *(const short8*)(Qs + (r0 + lo) * 64 + csw16);
    aq[1] = *(const short8*)(Qs + (r0 + 16 + lo) * 64 + csw16);
#pragma unroll
    for (int j = 0; j < 8; ++j)
        bk[j] = *(const short8*)(Ks + (j * 16 + lo) * 64 + csw16);

    f32x4 acc[2][8];
#pragma unroll
    for (int j = 0; j < 8; ++j) {
        f32x4 z = {0.f, 0.f, 0.f, 0.f};
        acc[0][j] = mfma16(aq[0], bk[j], z);
        acc[1][j] = mfma16(aq[1], bk[j], z);
    }

    // ---- bias + row max ----
    const float* eb = epb + (h << 14);
    float mrow[2][4], rsum[2][4];
#pragma unroll
    for (int mt = 0; mt < 2; ++mt)
#pragma unroll
        for (int ii = 0; ii < 4; ++ii) { mrow[mt][ii] = -1e30f; rsum[mt][ii] = 0.f; }

#pragma unroll
    for (int mt = 0; mt < 2; ++mt)
#pragma unroll
        for (int j = 0; j < 8; ++j)
#pragma unroll
            for (int ii = 0; ii < 4; ++ii) {
                const int r = r0 + mt * 16 + g * 4 + ii;
                const int c = j * 16 + lo;
                const float sv = acc[mt][j][ii] + eb[(r << 7) + c];
                acc[mt][j][ii] = sv;
                mrow[mt][ii] = fmaxf(mrow[mt][ii], sv);
            }
#pragma unroll
    for (int d = 1; d < 16; d <<= 1)
#pragma unroll
        for (int mt = 0; mt < 2; ++mt)
#pragma unroll
            for (int ii = 0; ii < 4; ++ii)
                mrow[mt][ii] = fmaxf(mrow[mt][ii], __shfl_xor(mrow[mt][ii], d, 64));

    __syncthreads();   // all waves done reading Qs/Ks -> Ps may overwrite

    // ---- exp -> Ps (per-wave private region), row sums ----
#pragma unroll
    for (int mt = 0; mt < 2; ++mt)
#pragma unroll
        for (int j = 0; j < 8; ++j)
#pragma unroll
            for (int ii = 0; ii < 4; ++ii) {
                const float p = __expf(acc[mt][j][ii] - mrow[mt][ii]);
                rsum[mt][ii] += p;
                Ps[w][mt * 16 + g * 4 + ii][j * 16 + lo] = f2bf(p);
            }
#pragma unroll
    for (int d = 1; d < 16; d <<= 1)
#pragma unroll
        for (int mt = 0; mt < 2; ++mt)
#pragma unroll
            for (int ii = 0; ii < 4; ++ii)
                rsum[mt][ii] += __shfl_xor(rsum[mt][ii], d, 64);

    // ---- O = P @ V ----
    f32x4 o[2][2] = {};
#pragma unroll
    for (int kk = 0; kk < 4; ++kk) {
        short8 av[2];
        av[0] = *(const short8*)(&Ps[w][lo][kk * 32 + g * 8]);
        av[1] = *(const short8*)(&Ps[w][16 + lo][kk * 32 + g * 8]);
#pragma unroll
        for (int dt = 0; dt < 2; ++dt) {
            const short8 bv = *(const short8*)(&Vt[dt * 16 + lo][kk * 32 + g * 8]);
            o[0][dt] = mfma16(av[0], bv, o[0][dt]);
            o[1][dt] = mfma16(av[1], bv, o[1][dt]);
        }
    }

    __syncthreads();   // all waves done reading Vt -> Os may overwrite

    // ---- normalize -> Os, coalesced int4 stores ----
#pragma unroll
    for (int mt = 0; mt < 2; ++mt)
#pragma unroll
        for (int dt = 0; dt < 2; ++dt)
#pragma unroll
            for (int ii = 0; ii < 4; ++ii)
                Os[r0 + mt * 16 + g * 4 + ii][dt * 16 + lo] =
                    f2bf(o[mt][dt][ii] / rsum[mt][ii]);
    __syncthreads();

    u16* op = aout + (size_t)b * 128 * 512 + h * 32;
#pragma unroll
    for (int it = 0; it < 2; ++it) {
        const int idx = tid + it * 256;          // 0..511
        const int r = idx >> 2, c = (idx & 3) * 8;
        *(int4*)(op + (size_t)r * 512 + c) = *(const int4*)(&Os[r][c]);
    }
}

// -------------------------------------------------------------- launch ----
extern "C" void kernel_launch(void* const* d_in, const int* in_sizes, int n_in,
                              void* d_out, int out_size, void* d_ws, size_t ws_size,
                              hipStream_t stream)
{
    const float* x      = (const float*)d_in[0];
    const float* qkv_w  = (const float*)d_in[1];
    const float* qkv_b  = (const float*)d_in[2];
    const float* proj_w = (const float*)d_in[3];
    const float* proj_b = (const float*)d_in[4];
    const float* btab   = (const float*)d_in[5];
    const int*   pidx   = (const int*)d_in[6];

    // workspace layout (bytes), total 1,076,887,552
    // xbf aliases attnbuf: x_bf16 is dead before attn writes its output.
    char* ws = (char*)d_ws;
    u16*   xbf      = (u16*)(ws);                        // 268,435,456
    u16*   attnbuf  = (u16*)(ws);                        // (alias)
    u16*   qkvw_bf  = (u16*)(ws + 268435456);            //   1,572,864
    u16*   projw_bf = (u16*)(ws + 270008320);            //     524,288
    float* epb      = (float*)(ws + 270532608);          //   1,048,576
    u16*   qbuf     = (u16*)(ws + 271581184);            // 268,435,456
    u16*   kbuf     = (u16*)(ws + 540016640);            // 268,435,456
    u16*   vbuf     = (u16*)(ws + 808452096);            // 268,435,456

    const float qscale = 0.17677669529663687f;           // 32^-0.5

    cvt_x_kernel<<<dim3(8192), dim3(256), 0, stream>>>(
        (const float4*)x, (int4*)xbf);

    prep_kernel<<<dim3(3072), dim3(256), 0, stream>>>(
        qkv_w, proj_w, btab, pidx, qkvw_bf, projw_bf, epb);

    // QKV: [262144,512]bf16 @ [1536,512]bf16^T -> Q/K/V head-major buffers
    gemm_bt<true><<<dim3(2048 * 12), dim3(256), 0, stream>>>(
        xbf, qkvw_bf, qkv_b, qbuf, kbuf, vbuf, 1536, 512, qscale);

    // fused window attention: 2048 windows x 16 heads
    attn_kernel<<<dim3(32768), dim3(256), 0, stream>>>(
        qbuf, kbuf, vbuf, epb, attnbuf);

    // proj: [262144,512]bf16 @ [512,512]bf16^T -> f32 (+bias)
    gemm_bt<false><<<dim3(2048 * 4), dim3(256), 0, stream>>>(
        attnbuf, projw_bf, proj_b, d_out, nullptr, nullptr, 512, 512, 1.0f);
}